// Round 2
// baseline (474.665 us; speedup 1.0000x reference)
//
#include <hip/hip_runtime.h>
#include <cstdint>

// ---------------------------------------------------------------------------
// TextBlock: BN -> {q,k,v} -> MHSA (NH=16, KD=16, D=64, N=1024) -> proj -> +res
//            -> BN -> MLP(1024, relu6) -> +res.   B=8, C=256.
// I/O is FLOAT32 (reference dtype). Intermediates bf16 for MFMA, fp32 accum.
// ---------------------------------------------------------------------------

typedef __attribute__((ext_vector_type(8))) short short8;
typedef __attribute__((ext_vector_type(4))) float floatx4;

__device__ __forceinline__ float b2f(unsigned short u) {
  union { unsigned int i; float f; } x; x.i = ((unsigned int)u) << 16; return x.f;
}
__device__ __forceinline__ unsigned short f2b(float f) {
  union { float f; unsigned int i; } x; x.f = f;
  unsigned int r = x.i + 0x7FFFu + ((x.i >> 16) & 1u);   // RNE
  return (unsigned short)(r >> 16);
}

// ---------------------------------------------------------------------------
// BatchNorm stats: one block per channel c (C=256). Stats over B=8 x N=1024.
// scale = g * rsqrt(var+eps); shift = b - mean*scale.   All fp32.
// ---------------------------------------------------------------------------
__global__ __launch_bounds__(256) void bn_stats(
    const float* __restrict__ x, const float* __restrict__ g,
    const float* __restrict__ bb, float* __restrict__ sc, float* __restrict__ sh) {
  int c = blockIdx.x, t = threadIdx.x;
  float s = 0.f, s2 = 0.f;
  for (int b = 0; b < 8; ++b) {
    const float* p = x + (((size_t)(b * 256 + c)) << 10);
    #pragma unroll
    for (int n = 0; n < 1024; n += 256) {
      float v = p[n + t]; s += v; s2 += v * v;
    }
  }
  #pragma unroll
  for (int o = 32; o > 0; o >>= 1) { s += __shfl_down(s, o, 64); s2 += __shfl_down(s2, o, 64); }
  __shared__ float rs[4], rs2[4];
  int w = t >> 6;
  if ((t & 63) == 0) { rs[w] = s; rs2[w] = s2; }
  __syncthreads();
  if (t == 0) {
    float S = rs[0] + rs[1] + rs[2] + rs[3];
    float S2 = rs2[0] + rs2[1] + rs2[2] + rs2[3];
    float m = S * (1.0f / 8192.0f);
    float var = S2 * (1.0f / 8192.0f) - m * m;
    float scale = g[c] * rsqrtf(var + 1e-5f);
    sc[c] = scale;
    sh[c] = bb[c] - m * scale;
  }
}

// y[i] = bf16(sc[c]*x[i] + sh[c]); x f32, y bf16. 4 elements/thread.
__global__ __launch_bounds__(256) void bn_apply(
    const float* __restrict__ x, const float* __restrict__ sc,
    const float* __restrict__ sh, unsigned short* __restrict__ y) {
  int i = blockIdx.x * 256 + threadIdx.x;     // group-of-4 index
  int c = ((i << 2) >> 10) & 255;
  float scl = sc[c], shf = sh[c];
  float4 u = ((const float4*)x)[i];
  unsigned short r0 = f2b(fmaf(u.x, scl, shf));
  unsigned short r1 = f2b(fmaf(u.y, scl, shf));
  unsigned short r2 = f2b(fmaf(u.z, scl, shf));
  unsigned short r3 = f2b(fmaf(u.w, scl, shf));
  uint2 o; o.x = (unsigned)r0 | ((unsigned)r1 << 16); o.y = (unsigned)r2 | ((unsigned)r3 << 16);
  ((uint2*)y)[i] = o;
}

// ---------------------------------------------------------------------------
// MFMA GEMM: out[b][row_off+row][col] = ( W[M,K]@Bsrc_b[K,N] + bias
//                                         (+relu6) (+res) )
// W f32 (converted to bf16 at staging). Bsrc bf16.
// BT=0: Bsrc is [K][N] k-major.  BT=1: Bsrc is [N][K] n-major.
// OB=1: out bf16 (ushort). OB=0: out f32.
// Block: 256 thr = 4 waves, tile 64x64, BK=32. Wave w: rows w*16..w*16+15.
// LDS rows padded to 40 el (80 B) -> 16B-aligned, uniform bank-group spread.
// ---------------------------------------------------------------------------
template <int BT, int OB>
__global__ __launch_bounds__(256, 2) void gemm_mfma(
    const float* __restrict__ W, const unsigned short* __restrict__ Bsrc,
    const float* __restrict__ bias, const float* __restrict__ res,
    void* __restrict__ outv, int M, int K, long long b_bstride,
    long long out_bstride, int out_row_off, int do_relu6) {
  const int NTOK = 1024;
  int n0 = blockIdx.x * 64, m0 = blockIdx.y * 64, b = blockIdx.z;
  int t = threadIdx.x, lane = t & 63, w = t >> 6;
  int ml = lane & 15, quad = lane >> 4;

  __shared__ unsigned short Wt[64][40];
  __shared__ unsigned short Yt[64][40];

  const unsigned short* Bp = Bsrc + (size_t)b * b_bstride;

  floatx4 acc0 = {0.f, 0.f, 0.f, 0.f}, acc1 = acc0, acc2 = acc0, acc3 = acc0;

  for (int k0 = 0; k0 < K; k0 += 32) {
    {  // stage W tile [64][32]: thread t loads 8 contiguous f32, cvt bf16
      int r = t >> 2, cg = (t & 3) * 8;
      const float* wp = W + (size_t)(m0 + r) * K + k0 + cg;
      float4 v0 = *(const float4*)(wp);
      float4 v1 = *(const float4*)(wp + 4);
      short8 wv;
      wv[0] = (short)f2b(v0.x); wv[1] = (short)f2b(v0.y);
      wv[2] = (short)f2b(v0.z); wv[3] = (short)f2b(v0.w);
      wv[4] = (short)f2b(v1.x); wv[5] = (short)f2b(v1.y);
      wv[6] = (short)f2b(v1.z); wv[7] = (short)f2b(v1.w);
      *(short8*)&Wt[r][cg] = wv;
    }
    if (BT == 0) {  // k-major source: 8 coalesced u16 loads -> 1 b128 LDS write
      int n = t & 63, kb = (t >> 6) * 8;
      short8 tv;
      #pragma unroll
      for (int j = 0; j < 8; ++j)
        tv[j] = (short)Bp[(size_t)(k0 + kb + j) * NTOK + n0 + n];
      *(short8*)&Yt[n][kb] = tv;
    } else {        // n-major source: direct 16B copy
      int nr = t >> 2, cg = (t & 3) * 8;
      uint4 v = *(const uint4*)(Bp + (size_t)(n0 + nr) * K + k0 + cg);
      *(uint4*)&Yt[nr][cg] = v;
    }
    __syncthreads();
    short8 a  = *(const short8*)&Wt[w * 16 + ml][quad * 8];
    short8 b0 = *(const short8*)&Yt[ 0 + ml][quad * 8];
    short8 b1 = *(const short8*)&Yt[16 + ml][quad * 8];
    short8 b2 = *(const short8*)&Yt[32 + ml][quad * 8];
    short8 b3 = *(const short8*)&Yt[48 + ml][quad * 8];
    acc0 = __builtin_amdgcn_mfma_f32_16x16x32_bf16(a, b0, acc0, 0, 0, 0);
    acc1 = __builtin_amdgcn_mfma_f32_16x16x32_bf16(a, b1, acc1, 0, 0, 0);
    acc2 = __builtin_amdgcn_mfma_f32_16x16x32_bf16(a, b2, acc2, 0, 0, 0);
    acc3 = __builtin_amdgcn_mfma_f32_16x16x32_bf16(a, b3, acc3, 0, 0, 0);
    __syncthreads();
  }

  int row_base = m0 + w * 16 + quad * 4;
  #pragma unroll
  for (int c = 0; c < 4; ++c) {
    floatx4 acc = (c == 0) ? acc0 : (c == 1) ? acc1 : (c == 2) ? acc2 : acc3;
    int col = n0 + c * 16 + ml;
    #pragma unroll
    for (int r = 0; r < 4; ++r) {
      int row = row_base + r;
      float v = acc[r] + bias[row];
      if (do_relu6) v = fminf(fmaxf(v, 0.f), 6.f);
      if (res) v += res[(size_t)b * M * NTOK + (size_t)row * NTOK + col];
      size_t oidx = (size_t)b * out_bstride + (size_t)(out_row_off + row) * NTOK + col;
      if (OB) ((unsigned short*)outv)[oidx] = f2b(v);
      else    ((float*)outv)[oidx] = v;
    }
  }
}

// ---------------------------------------------------------------------------
// Attention: one block per (b, h, 16-row n-tile). 8*16*64 = 8192 blocks.
// Phase 1 (VALU): wave w computes rows w*4..w*4+3 of S = (q.kT)*4, full
//   softmax in regs (scale folded as 4*log2e -> exp2), normalized P -> LDS.
// Phase 2 (MFMA): wave w computes d-tile w*16: O[16n x 16d] = P @ V, K=1024.
// qkv layout (bf16): [b][1536][1024]; rows 0..255 q, 256..511 k, 512..1535 v.
// Output ot[b][n][dh] bf16 (n-major, feeds BT=1 proj GEMM).
// ---------------------------------------------------------------------------
__global__ __launch_bounds__(256, 2) void attn_kernel(
    const unsigned short* __restrict__ qkv, unsigned short* __restrict__ ot) {
  int bx = blockIdx.x;
  int nt = bx & 63, h = (bx >> 6) & 15, b = bx >> 10;
  int t = threadIdx.x, lane = t & 63, w = t >> 6;
  __shared__ unsigned short P[16][1032];   // padded: uniform bank groups

  const size_t headq = ((size_t)b * 1536 + h * 16) * 1024;
  const size_t headk = ((size_t)b * 1536 + 256 + h * 16) * 1024;
  const size_t headv = ((size_t)b * 1536 + 512 + h * 64) * 1024;

  const float SC = 4.0f * 1.4426950408889634f;  // sqrt(KD)=4, fold log2(e)
  float q[4][16];
  #pragma unroll
  for (int r = 0; r < 4; ++r) {
    int n = nt * 16 + w * 4 + r;
    #pragma unroll
    for (int kd = 0; kd < 16; ++kd)
      q[r][kd] = b2f(qkv[headq + (size_t)kd * 1024 + n]) * SC;
  }
  float s[4][16];
  #pragma unroll
  for (int r = 0; r < 4; ++r)
    #pragma unroll
    for (int j = 0; j < 16; ++j) s[r][j] = 0.f;

  #pragma unroll
  for (int j = 0; j < 16; ++j) {          // lane handles m = j*64 + lane
    int m = j * 64 + lane;
    float kv[16];
    #pragma unroll
    for (int kd = 0; kd < 16; ++kd) kv[kd] = b2f(qkv[headk + (size_t)kd * 1024 + m]);
    #pragma unroll
    for (int r = 0; r < 4; ++r)
      #pragma unroll
      for (int kd = 0; kd < 16; ++kd) s[r][j] = fmaf(q[r][kd], kv[kd], s[r][j]);
  }

  #pragma unroll
  for (int r = 0; r < 4; ++r) {
    float mx = s[r][0];
    #pragma unroll
    for (int j = 1; j < 16; ++j) mx = fmaxf(mx, s[r][j]);
    #pragma unroll
    for (int o = 32; o > 0; o >>= 1) mx = fmaxf(mx, __shfl_xor(mx, o, 64));
    float p[16], sum = 0.f;
    #pragma unroll
    for (int j = 0; j < 16; ++j) { p[j] = __builtin_amdgcn_exp2f(s[r][j] - mx); sum += p[j]; }
    #pragma unroll
    for (int o = 32; o > 0; o >>= 1) sum += __shfl_xor(sum, o, 64);
    float inv = 1.0f / sum;
    #pragma unroll
    for (int j = 0; j < 16; ++j) P[w * 4 + r][j * 64 + lane] = f2b(p[j] * inv);
  }
  __syncthreads();

  int ml = lane & 15, quad = lane >> 4;
  int d0 = w * 16;
  floatx4 oacc = {0.f, 0.f, 0.f, 0.f};
  const unsigned short* vp = qkv + headv + (size_t)(d0 + ml) * 1024 + quad * 8;
  #pragma unroll 4
  for (int ks = 0; ks < 32; ++ks) {
    short8 a = *(const short8*)&P[ml][ks * 32 + quad * 8];        // A: P[n][m]
    short8 bf = *(const short8*)(vp + ks * 32);                   // B: V[m][d]
    oacc = __builtin_amdgcn_mfma_f32_16x16x32_bf16(a, bf, oacc, 0, 0, 0);
  }
  int dg = h * 64 + d0 + ml;
  #pragma unroll
  for (int r = 0; r < 4; ++r) {
    int n = nt * 16 + quad * 4 + r;
    ot[(((size_t)b << 10) + n) * 1024 + dg] = f2b(oacc[r]);
  }
}

// ---------------------------------------------------------------------------
extern "C" void kernel_launch(void* const* d_in, const int* in_sizes, int n_in,
                              void* d_out, int out_size, void* d_ws, size_t ws_size,
                              hipStream_t stream) {
  const float* x   = (const float*)d_in[0];
  const float* g1  = (const float*)d_in[1];
  const float* b1  = (const float*)d_in[2];
  const float* wq  = (const float*)d_in[3];
  const float* bq  = (const float*)d_in[4];
  const float* wk  = (const float*)d_in[5];
  const float* bk  = (const float*)d_in[6];
  const float* wv  = (const float*)d_in[7];
  const float* bv  = (const float*)d_in[8];
  const float* wp  = (const float*)d_in[9];
  const float* bp  = (const float*)d_in[10];
  const float* g2  = (const float*)d_in[11];
  const float* b2  = (const float*)d_in[12];
  const float* w1  = (const float*)d_in[13];
  const float* bb1 = (const float*)d_in[14];
  const float* w2  = (const float*)d_in[15];
  const float* bb2 = (const float*)d_in[16];

  char* ws = (char*)d_ws;
  float* sc1 = (float*)ws;
  float* sh1 = sc1 + 256;
  float* sc2 = sh1 + 256;
  float* sh2 = sc2 + 256;
  unsigned short* y   = (unsigned short*)(ws + 4096);     // bf16 [8][256][1024] (y1, then y2)
  unsigned short* qkv = y   + (size_t)2 * 1024 * 1024;    // bf16 [8][1536][1024]
  unsigned short* ot  = qkv + (size_t)8 * 1536 * 1024;    // bf16 [8][1024][1024] (o_t, then h)
  float*          xf1 = (float*)(ot + (size_t)8 * 1024 * 1024);  // f32 [8][256][1024]
  unsigned short* hb  = ot;                               // reuse (o_t dead after proj)
  float* outp = (float*)d_out;
  const float* nul = nullptr;

  // --- attention branch ---
  bn_stats<<<dim3(256), dim3(256), 0, stream>>>(x, g1, b1, sc1, sh1);
  bn_apply<<<dim3(2048), dim3(256), 0, stream>>>(x, sc1, sh1, y);
  gemm_mfma<0, 1><<<dim3(16, 4, 8), dim3(256), 0, stream>>>(
      wq, y, bq, nul, qkv, 256, 256, 256ll * 1024, 1536ll * 1024, 0, 0);
  gemm_mfma<0, 1><<<dim3(16, 4, 8), dim3(256), 0, stream>>>(
      wk, y, bk, nul, qkv, 256, 256, 256ll * 1024, 1536ll * 1024, 256, 0);
  gemm_mfma<0, 1><<<dim3(16, 16, 8), dim3(256), 0, stream>>>(
      wv, y, bv, nul, qkv, 1024, 256, 256ll * 1024, 1536ll * 1024, 512, 0);
  attn_kernel<<<dim3(8192), dim3(256), 0, stream>>>(qkv, ot);
  gemm_mfma<1, 0><<<dim3(16, 4, 8), dim3(256), 0, stream>>>(
      wp, ot, bp, x, xf1, 256, 1024, 1024ll * 1024, 256ll * 1024, 0, 0);

  // --- MLP branch ---
  bn_stats<<<dim3(256), dim3(256), 0, stream>>>(xf1, g2, b2, sc2, sh2);
  bn_apply<<<dim3(2048), dim3(256), 0, stream>>>(xf1, sc2, sh2, y);
  gemm_mfma<0, 1><<<dim3(16, 16, 8), dim3(256), 0, stream>>>(
      w1, y, bb1, nul, hb, 1024, 256, 256ll * 1024, 1024ll * 1024, 0, 1);
  gemm_mfma<0, 0><<<dim3(16, 4, 8), dim3(256), 0, stream>>>(
      w2, hb, bb2, xf1, outp, 256, 1024, 1024ll * 1024, 256ll * 1024, 0, 0);
}

// Round 3
// 369.448 us; speedup vs baseline: 1.2848x; 1.2848x over previous
//
#include <hip/hip_runtime.h>
#include <cstdint>

// ---------------------------------------------------------------------------
// TextBlock: BN -> {q,k,v} -> MHSA (NH=16, KD=16, D=64, N=1024) -> proj -> +res
//            -> BN -> MLP(1024, relu6) -> +res.   B=8, C=256.
// I/O is FLOAT32. Intermediates bf16 for MFMA, fp32 accumulation.
// R3: scores via MFMA (Q/K written per-head-transposed by the QKV GEMM).
// ---------------------------------------------------------------------------

typedef __attribute__((ext_vector_type(8))) short short8;
typedef __attribute__((ext_vector_type(4))) float floatx4;

__device__ __forceinline__ float b2f(unsigned short u) {
  union { unsigned int i; float f; } x; x.i = ((unsigned int)u) << 16; return x.f;
}
__device__ __forceinline__ unsigned short f2b(float f) {
  union { float f; unsigned int i; } x; x.f = f;
  unsigned int r = x.i + 0x7FFFu + ((x.i >> 16) & 1u);   // RNE
  return (unsigned short)(r >> 16);
}

// ---------------------------------------------------------------------------
// BatchNorm stats: one block per channel c (C=256). Stats over B=8 x N=1024.
// ---------------------------------------------------------------------------
__global__ __launch_bounds__(256) void bn_stats(
    const float* __restrict__ x, const float* __restrict__ g,
    const float* __restrict__ bb, float* __restrict__ sc, float* __restrict__ sh) {
  int c = blockIdx.x, t = threadIdx.x;
  float s = 0.f, s2 = 0.f;
  for (int b = 0; b < 8; ++b) {
    const float* p = x + (((size_t)(b * 256 + c)) << 10);
    #pragma unroll
    for (int n = 0; n < 1024; n += 256) {
      float v = p[n + t]; s += v; s2 += v * v;
    }
  }
  #pragma unroll
  for (int o = 32; o > 0; o >>= 1) { s += __shfl_down(s, o, 64); s2 += __shfl_down(s2, o, 64); }
  __shared__ float rs[4], rs2[4];
  int w = t >> 6;
  if ((t & 63) == 0) { rs[w] = s; rs2[w] = s2; }
  __syncthreads();
  if (t == 0) {
    float S = rs[0] + rs[1] + rs[2] + rs[3];
    float S2 = rs2[0] + rs2[1] + rs2[2] + rs2[3];
    float m = S * (1.0f / 8192.0f);
    float var = S2 * (1.0f / 8192.0f) - m * m;
    float scale = g[c] * rsqrtf(var + 1e-5f);
    sc[c] = scale;
    sh[c] = bb[c] - m * scale;
  }
}

// y[i] = bf16(sc[c]*x[i] + sh[c]); x f32, y bf16. 4 elements/thread.
__global__ __launch_bounds__(256) void bn_apply(
    const float* __restrict__ x, const float* __restrict__ sc,
    const float* __restrict__ sh, unsigned short* __restrict__ y) {
  int i = blockIdx.x * 256 + threadIdx.x;     // group-of-4 index
  int c = ((i << 2) >> 10) & 255;
  float scl = sc[c], shf = sh[c];
  float4 u = ((const float4*)x)[i];
  unsigned short r0 = f2b(fmaf(u.x, scl, shf));
  unsigned short r1 = f2b(fmaf(u.y, scl, shf));
  unsigned short r2 = f2b(fmaf(u.z, scl, shf));
  unsigned short r3 = f2b(fmaf(u.w, scl, shf));
  uint2 o; o.x = (unsigned)r0 | ((unsigned)r1 << 16); o.y = (unsigned)r2 | ((unsigned)r3 << 16);
  ((uint2*)y)[i] = o;
}

// ---------------------------------------------------------------------------
// MFMA GEMM: out = W[M,K]@Bsrc_b[K,N] + bias (+relu6) (+res)
// BT=0: Bsrc [K][N] k-major.  BT=1: Bsrc [N][K] n-major.
// OB=1: out bf16. OB=0: out f32.
// OT=1: per-head transposed bf16 write: out[((b*16 + row>>4)*1024 + col)*16
//        + (row&15)]  (rows are h*16+kd; gives [b][h][n][kd] layout).
// ---------------------------------------------------------------------------
template <int BT, int OB, int OT>
__global__ __launch_bounds__(256, 2) void gemm_mfma(
    const float* __restrict__ W, const unsigned short* __restrict__ Bsrc,
    const float* __restrict__ bias, const float* __restrict__ res,
    void* __restrict__ outv, int M, int K, long long b_bstride,
    long long out_bstride, int out_row_off, int do_relu6) {
  const int NTOK = 1024;
  int n0 = blockIdx.x * 64, m0 = blockIdx.y * 64, b = blockIdx.z;
  int t = threadIdx.x, lane = t & 63, w = t >> 6;
  int ml = lane & 15, quad = lane >> 4;

  __shared__ unsigned short Wt[64][40];
  __shared__ unsigned short Yt[64][40];

  const unsigned short* Bp = Bsrc + (size_t)b * b_bstride;

  floatx4 acc0 = {0.f, 0.f, 0.f, 0.f}, acc1 = acc0, acc2 = acc0, acc3 = acc0;

  for (int k0 = 0; k0 < K; k0 += 32) {
    {  // stage W tile [64][32]: thread t loads 8 contiguous f32, cvt bf16
      int r = t >> 2, cg = (t & 3) * 8;
      const float* wp = W + (size_t)(m0 + r) * K + k0 + cg;
      float4 v0 = *(const float4*)(wp);
      float4 v1 = *(const float4*)(wp + 4);
      short8 wv;
      wv[0] = (short)f2b(v0.x); wv[1] = (short)f2b(v0.y);
      wv[2] = (short)f2b(v0.z); wv[3] = (short)f2b(v0.w);
      wv[4] = (short)f2b(v1.x); wv[5] = (short)f2b(v1.y);
      wv[6] = (short)f2b(v1.z); wv[7] = (short)f2b(v1.w);
      *(short8*)&Wt[r][cg] = wv;
    }
    if (BT == 0) {  // k-major source: 8 coalesced u16 loads -> 1 b128 LDS write
      int n = t & 63, kb = (t >> 6) * 8;
      short8 tv;
      #pragma unroll
      for (int j = 0; j < 8; ++j)
        tv[j] = (short)Bp[(size_t)(k0 + kb + j) * NTOK + n0 + n];
      *(short8*)&Yt[n][kb] = tv;
    } else {        // n-major source: direct 16B copy
      int nr = t >> 2, cg = (t & 3) * 8;
      uint4 v = *(const uint4*)(Bp + (size_t)(n0 + nr) * K + k0 + cg);
      *(uint4*)&Yt[nr][cg] = v;
    }
    __syncthreads();
    short8 a  = *(const short8*)&Wt[w * 16 + ml][quad * 8];
    short8 b0 = *(const short8*)&Yt[ 0 + ml][quad * 8];
    short8 b1 = *(const short8*)&Yt[16 + ml][quad * 8];
    short8 b2 = *(const short8*)&Yt[32 + ml][quad * 8];
    short8 b3 = *(const short8*)&Yt[48 + ml][quad * 8];
    acc0 = __builtin_amdgcn_mfma_f32_16x16x32_bf16(a, b0, acc0, 0, 0, 0);
    acc1 = __builtin_amdgcn_mfma_f32_16x16x32_bf16(a, b1, acc1, 0, 0, 0);
    acc2 = __builtin_amdgcn_mfma_f32_16x16x32_bf16(a, b2, acc2, 0, 0, 0);
    acc3 = __builtin_amdgcn_mfma_f32_16x16x32_bf16(a, b3, acc3, 0, 0, 0);
    __syncthreads();
  }

  int row_base = m0 + w * 16 + quad * 4;
  #pragma unroll
  for (int c = 0; c < 4; ++c) {
    floatx4 acc = (c == 0) ? acc0 : (c == 1) ? acc1 : (c == 2) ? acc2 : acc3;
    int col = n0 + c * 16 + ml;
    #pragma unroll
    for (int r = 0; r < 4; ++r) {
      int row = row_base + r;
      float v = acc[r] + bias[row];
      if (do_relu6) v = fminf(fmaxf(v, 0.f), 6.f);
      if (res) v += res[(size_t)b * M * NTOK + (size_t)row * NTOK + col];
      if (OT) {
        size_t oidx = (((size_t)b * 16 + (row >> 4)) * 1024 + col) * 16 + (row & 15);
        ((unsigned short*)outv)[oidx] = f2b(v);
      } else {
        size_t oidx = (size_t)b * out_bstride + (size_t)(out_row_off + row) * NTOK + col;
        if (OB) ((unsigned short*)outv)[oidx] = f2b(v);
        else    ((float*)outv)[oidx] = v;
      }
    }
  }
}

// ---------------------------------------------------------------------------
// Attention v2: one block per (b, h, 16-row n-tile). 8192 blocks, 4 waves.
// Phase 1 (MFMA): wave w computes S rows (all 16) x cols w*256..w*256+255 via
//   16 MFMAs 16x16x32 (kd zero-padded 16->32); frags load direct from global
//   qt/kt [b][h][n][16] (coalesced b128). Softmax in regs + tiny LDS combine.
// Phase 2 (MFMA): wave w computes d-tile w*16: O = P @ V, K=1024, V from
//   global [b][dh][m].  Output ot[b][n][dh] (n-major, feeds BT=1 proj GEMM).
// ---------------------------------------------------------------------------
__global__ __launch_bounds__(256, 4) void attn_kernel(
    const unsigned short* __restrict__ qt, const unsigned short* __restrict__ kt,
    const unsigned short* __restrict__ vt, unsigned short* __restrict__ ot) {
  int bx = blockIdx.x;
  int nt = bx & 63, h = (bx >> 6) & 15, b = bx >> 10;
  int t = threadIdx.x, lane = t & 63, w = t >> 6;
  int ml = lane & 15, quad = lane >> 4;
  __shared__ unsigned short P[16][1032];   // padded: uniform bank groups
  __shared__ float Mw[4][16];
  __shared__ float Sw[4][16];

  // ---- phase 1: S = Q K^T via MFMA ----
  const size_t qbase = (((size_t)b * 16 + h) * 1024 + (size_t)nt * 16) * 16;
  const size_t kbase = (((size_t)b * 16 + h) * 1024) * 16;

  short8 afrag = {0, 0, 0, 0, 0, 0, 0, 0};          // A[n=ml][kd=quad*8+j]
  if (quad < 2) afrag = *(const short8*)(qt + qbase + (size_t)ml * 16 + quad * 8);

  floatx4 acc[16];
  #pragma unroll
  for (int i = 0; i < 16; ++i) acc[i] = (floatx4){0.f, 0.f, 0.f, 0.f};

  #pragma unroll
  for (int ti = 0; ti < 16; ++ti) {
    int m0 = (w * 16 + ti) * 16;
    short8 bfrag = {0, 0, 0, 0, 0, 0, 0, 0};        // B[m=ml][kd=quad*8+j]
    if (quad < 2) bfrag = *(const short8*)(kt + kbase + (size_t)(m0 + ml) * 16 + quad * 8);
    acc[ti] = __builtin_amdgcn_mfma_f32_16x16x32_bf16(afrag, bfrag, acc[ti], 0, 0, 0);
  }
  // lane holds S[row=quad*4+r][col=w*256+ti*16+ml] in acc[ti][r]

  const float SC = 5.770780163555851f;   // 4 * log2(e): softmax(S*4) via exp2
  float mx[4], sm[4];
  #pragma unroll
  for (int r = 0; r < 4; ++r) {
    float m = acc[0][r];
    #pragma unroll
    for (int ti = 1; ti < 16; ++ti) m = fmaxf(m, acc[ti][r]);
    #pragma unroll
    for (int o = 1; o < 16; o <<= 1) m = fmaxf(m, __shfl_xor(m, o, 64));
    mx[r] = m;
  }
  if (ml == 0) {
    #pragma unroll
    for (int r = 0; r < 4; ++r) Mw[w][quad * 4 + r] = mx[r];
  }
  __syncthreads();
  #pragma unroll
  for (int r = 0; r < 4; ++r) {
    int row = quad * 4 + r;
    float m = fmaxf(fmaxf(Mw[0][row], Mw[1][row]), fmaxf(Mw[2][row], Mw[3][row]));
    float s = 0.f;
    #pragma unroll
    for (int ti = 0; ti < 16; ++ti) {
      float p = __builtin_amdgcn_exp2f((acc[ti][r] - m) * SC);
      acc[ti][r] = p; s += p;
    }
    #pragma unroll
    for (int o = 1; o < 16; o <<= 1) s += __shfl_xor(s, o, 64);
    sm[r] = s;
  }
  if (ml == 0) {
    #pragma unroll
    for (int r = 0; r < 4; ++r) Sw[w][quad * 4 + r] = sm[r];
  }
  __syncthreads();
  #pragma unroll
  for (int r = 0; r < 4; ++r) {
    int row = quad * 4 + r;
    float inv = 1.0f / (Sw[0][row] + Sw[1][row] + Sw[2][row] + Sw[3][row]);
    #pragma unroll
    for (int ti = 0; ti < 16; ++ti)
      P[row][w * 256 + ti * 16 + ml] = f2b(acc[ti][r] * inv);
  }
  __syncthreads();

  // ---- phase 2: O = P @ V ----
  const size_t headv = ((size_t)b * 1024 + h * 64) * 1024;
  int d0 = w * 16;
  floatx4 oacc = {0.f, 0.f, 0.f, 0.f};
  const unsigned short* vp = vt + headv + (size_t)(d0 + ml) * 1024 + quad * 8;
  #pragma unroll 4
  for (int ks = 0; ks < 32; ++ks) {
    short8 a = *(const short8*)&P[ml][ks * 32 + quad * 8];        // A: P[n][m]
    short8 bf = *(const short8*)(vp + ks * 32);                   // B: V[m][d]
    oacc = __builtin_amdgcn_mfma_f32_16x16x32_bf16(a, bf, oacc, 0, 0, 0);
  }
  int dg = h * 64 + d0 + ml;
  #pragma unroll
  for (int r = 0; r < 4; ++r) {
    int n = nt * 16 + quad * 4 + r;
    ot[(((size_t)b << 10) + n) * 1024 + dg] = f2b(oacc[r]);
  }
}

// ---------------------------------------------------------------------------
extern "C" void kernel_launch(void* const* d_in, const int* in_sizes, int n_in,
                              void* d_out, int out_size, void* d_ws, size_t ws_size,
                              hipStream_t stream) {
  const float* x   = (const float*)d_in[0];
  const float* g1  = (const float*)d_in[1];
  const float* b1  = (const float*)d_in[2];
  const float* wq  = (const float*)d_in[3];
  const float* bq  = (const float*)d_in[4];
  const float* wk  = (const float*)d_in[5];
  const float* bk  = (const float*)d_in[6];
  const float* wv  = (const float*)d_in[7];
  const float* bv  = (const float*)d_in[8];
  const float* wp  = (const float*)d_in[9];
  const float* bp  = (const float*)d_in[10];
  const float* g2  = (const float*)d_in[11];
  const float* b2  = (const float*)d_in[12];
  const float* w1  = (const float*)d_in[13];
  const float* bb1 = (const float*)d_in[14];
  const float* w2  = (const float*)d_in[15];
  const float* bb2 = (const float*)d_in[16];

  char* ws = (char*)d_ws;
  float* sc1 = (float*)ws;
  float* sh1 = sc1 + 256;
  float* sc2 = sh1 + 256;
  float* sh2 = sc2 + 256;
  unsigned short* y   = (unsigned short*)(ws + 4096);     // bf16 [8][256][1024]
  unsigned short* qt  = y   + (size_t)2 * 1024 * 1024;    // bf16 [8][16][1024][16]
  unsigned short* kt  = qt  + (size_t)2 * 1024 * 1024;    // bf16 [8][16][1024][16]
  unsigned short* vt  = kt  + (size_t)2 * 1024 * 1024;    // bf16 [8][1024][1024]
  unsigned short* ot  = vt  + (size_t)8 * 1024 * 1024;    // bf16 [8][1024][1024]
  float*          xf1 = (float*)(ot + (size_t)8 * 1024 * 1024);  // f32 [8][256][1024]
  unsigned short* hb  = ot;                               // reuse (o_t dead after proj)
  float* outp = (float*)d_out;
  const float* nul = nullptr;

  // --- attention branch ---
  bn_stats<<<dim3(256), dim3(256), 0, stream>>>(x, g1, b1, sc1, sh1);
  bn_apply<<<dim3(2048), dim3(256), 0, stream>>>(x, sc1, sh1, y);
  gemm_mfma<0, 1, 1><<<dim3(16, 4, 8), dim3(256), 0, stream>>>(
      wq, y, bq, nul, qt, 256, 256, 256ll * 1024, 0, 0, 0);
  gemm_mfma<0, 1, 1><<<dim3(16, 4, 8), dim3(256), 0, stream>>>(
      wk, y, bk, nul, kt, 256, 256, 256ll * 1024, 0, 0, 0);
  gemm_mfma<0, 1, 0><<<dim3(16, 16, 8), dim3(256), 0, stream>>>(
      wv, y, bv, nul, vt, 1024, 256, 256ll * 1024, 1024ll * 1024, 0, 0);
  attn_kernel<<<dim3(8192), dim3(256), 0, stream>>>(qt, kt, vt, ot);
  gemm_mfma<1, 0, 0><<<dim3(16, 4, 8), dim3(256), 0, stream>>>(
      wp, ot, bp, x, xf1, 256, 1024, 1024ll * 1024, 256ll * 1024, 0, 0);

  // --- MLP branch ---
  bn_stats<<<dim3(256), dim3(256), 0, stream>>>(xf1, g2, b2, sc2, sh2);
  bn_apply<<<dim3(2048), dim3(256), 0, stream>>>(xf1, sc2, sh2, y);
  gemm_mfma<0, 1, 0><<<dim3(16, 16, 8), dim3(256), 0, stream>>>(
      w1, y, bb1, nul, hb, 1024, 256, 256ll * 1024, 1024ll * 1024, 0, 1);
  gemm_mfma<0, 0, 0><<<dim3(16, 4, 8), dim3(256), 0, stream>>>(
      w2, hb, bb2, xf1, outp, 256, 1024, 1024ll * 1024, 256ll * 1024, 0, 0);
}

// Round 4
// 351.759 us; speedup vs baseline: 1.3494x; 1.0503x over previous
//
#include <hip/hip_runtime.h>
#include <hip/hip_bf16.h>
#include <cstdint>

// ---------------------------------------------------------------------------
// TextBlock: BN -> {q,k,v} -> MHSA (NH=16, KD=16, D=64, N=1024) -> proj -> +res
//            -> BN -> MLP(1024, relu6) -> +res.   B=8, C=256.
// I/O FLOAT32. Intermediates bf16 for MFMA, fp32 accumulation.
// R4: attn S^T trick (b64 P-writes), deferred softmax norm, packed bf16 cvt,
//     4-acc phase-2 pipeline, pre-converted bf16 weights.
// ---------------------------------------------------------------------------

typedef __attribute__((ext_vector_type(8))) short short8;
typedef __attribute__((ext_vector_type(4))) float floatx4;

__device__ __forceinline__ float b2f(unsigned short u) {
  union { unsigned int i; float f; } x; x.i = ((unsigned int)u) << 16; return x.f;
}
__device__ __forceinline__ unsigned short f2b(float f) {
  union { float f; unsigned int i; } x; x.f = f;
  unsigned int r = x.i + 0x7FFFu + ((x.i >> 16) & 1u);   // RNE
  return (unsigned short)(r >> 16);
}
// packed f32x2 -> bf16x2 (v_cvt_pk_bf16_f32 on gfx950)
__device__ __forceinline__ unsigned int f2b2(float a, float b) {
  __hip_bfloat162 h = __float22bfloat162_rn(make_float2(a, b));
  union { __hip_bfloat162 v; unsigned int u; } x; x.v = h; return x.u;
}

// ---------------------------------------------------------------------------
// Convert the 6 weight matrices f32 -> bf16 into one ws region.
// Element counts: wq 65536, wk 65536, wv 262144, wp 262144, w1 262144, w2 262144.
// ---------------------------------------------------------------------------
__global__ __launch_bounds__(256) void cvt_weights(
    const float* __restrict__ s0, const float* __restrict__ s1,
    const float* __restrict__ s2, const float* __restrict__ s3,
    const float* __restrict__ s4, const float* __restrict__ s5,
    unsigned short* __restrict__ dst) {
  int i = blockIdx.x * 256 + threadIdx.x;   // float4-group index
  if (i >= 294912) return;
  const float* s; int li; size_t dbase;
  if (i < 16384)       { s = s0; li = i;          dbase = 0; }
  else if (i < 32768)  { s = s1; li = i - 16384;  dbase = 65536; }
  else if (i < 98304)  { s = s2; li = i - 32768;  dbase = 131072; }
  else if (i < 163840) { s = s3; li = i - 98304;  dbase = 393216; }
  else if (i < 229376) { s = s4; li = i - 163840; dbase = 655360; }
  else                 { s = s5; li = i - 229376; dbase = 917504; }
  float4 v = ((const float4*)s)[li];
  uint2 o; o.x = f2b2(v.x, v.y); o.y = f2b2(v.z, v.w);
  ((uint2*)(dst + dbase))[li] = o;
}

// ---------------------------------------------------------------------------
// BatchNorm stats: one block per channel c (C=256). Stats over B=8 x N=1024.
// ---------------------------------------------------------------------------
__global__ __launch_bounds__(256) void bn_stats(
    const float* __restrict__ x, const float* __restrict__ g,
    const float* __restrict__ bb, float* __restrict__ sc, float* __restrict__ sh) {
  int c = blockIdx.x, t = threadIdx.x;
  float s = 0.f, s2 = 0.f;
  for (int b = 0; b < 8; ++b) {
    const float* p = x + (((size_t)(b * 256 + c)) << 10);
    #pragma unroll
    for (int n = 0; n < 1024; n += 256) {
      float v = p[n + t]; s += v; s2 += v * v;
    }
  }
  #pragma unroll
  for (int o = 32; o > 0; o >>= 1) { s += __shfl_down(s, o, 64); s2 += __shfl_down(s2, o, 64); }
  __shared__ float rs[4], rs2[4];
  int w = t >> 6;
  if ((t & 63) == 0) { rs[w] = s; rs2[w] = s2; }
  __syncthreads();
  if (t == 0) {
    float S = rs[0] + rs[1] + rs[2] + rs[3];
    float S2 = rs2[0] + rs2[1] + rs2[2] + rs2[3];
    float m = S * (1.0f / 8192.0f);
    float var = S2 * (1.0f / 8192.0f) - m * m;
    float scale = g[c] * rsqrtf(var + 1e-5f);
    sc[c] = scale;
    sh[c] = bb[c] - m * scale;
  }
}

// y[i] = bf16(sc[c]*x[i] + sh[c]); x f32, y bf16. 4 elements/thread.
__global__ __launch_bounds__(256) void bn_apply(
    const float* __restrict__ x, const float* __restrict__ sc,
    const float* __restrict__ sh, unsigned short* __restrict__ y) {
  int i = blockIdx.x * 256 + threadIdx.x;     // group-of-4 index
  int c = ((i << 2) >> 10) & 255;
  float scl = sc[c], shf = sh[c];
  float4 u = ((const float4*)x)[i];
  uint2 o;
  o.x = f2b2(fmaf(u.x, scl, shf), fmaf(u.y, scl, shf));
  o.y = f2b2(fmaf(u.z, scl, shf), fmaf(u.w, scl, shf));
  ((uint2*)y)[i] = o;
}

// ---------------------------------------------------------------------------
// MFMA GEMM: out = W[M,K]@Bsrc_b[K,N] + bias (+relu6) (+res)
// W bf16 (pre-converted). Bsrc bf16.
// BT=0: Bsrc [K][N] k-major.  BT=1: Bsrc [N][K] n-major.
// OB=1: out bf16. OB=0: out f32.
// OT=1: per-head transposed bf16 write -> [b][h][n][16kd] layout.
// ---------------------------------------------------------------------------
template <int BT, int OB, int OT>
__global__ __launch_bounds__(256, 2) void gemm_mfma(
    const unsigned short* __restrict__ W, const unsigned short* __restrict__ Bsrc,
    const float* __restrict__ bias, const float* __restrict__ res,
    void* __restrict__ outv, int M, int K, long long b_bstride,
    long long out_bstride, int out_row_off, int do_relu6) {
  const int NTOK = 1024;
  int n0 = blockIdx.x * 64, m0 = blockIdx.y * 64, b = blockIdx.z;
  int t = threadIdx.x, lane = t & 63, w = t >> 6;
  int ml = lane & 15, quad = lane >> 4;

  __shared__ unsigned short Wt[64][40];
  __shared__ unsigned short Yt[64][40];

  const unsigned short* Bp = Bsrc + (size_t)b * b_bstride;

  floatx4 acc0 = {0.f, 0.f, 0.f, 0.f}, acc1 = acc0, acc2 = acc0, acc3 = acc0;

  for (int k0 = 0; k0 < K; k0 += 32) {
    {  // stage W tile [64][32]: pure b128 copy (bf16 weights)
      int r = t >> 2, cg = (t & 3) * 8;
      *(uint4*)&Wt[r][cg] = *(const uint4*)(W + (size_t)(m0 + r) * K + k0 + cg);
    }
    if (BT == 0) {  // k-major source: 8 coalesced u16 loads -> 1 b128 LDS write
      int n = t & 63, kb = (t >> 6) * 8;
      short8 tv;
      #pragma unroll
      for (int j = 0; j < 8; ++j)
        tv[j] = (short)Bp[(size_t)(k0 + kb + j) * NTOK + n0 + n];
      *(short8*)&Yt[n][kb] = tv;
    } else {        // n-major source: direct 16B copy
      int nr = t >> 2, cg = (t & 3) * 8;
      uint4 v = *(const uint4*)(Bp + (size_t)(n0 + nr) * K + k0 + cg);
      *(uint4*)&Yt[nr][cg] = v;
    }
    __syncthreads();
    short8 a  = *(const short8*)&Wt[w * 16 + ml][quad * 8];
    short8 b0 = *(const short8*)&Yt[ 0 + ml][quad * 8];
    short8 b1 = *(const short8*)&Yt[16 + ml][quad * 8];
    short8 b2 = *(const short8*)&Yt[32 + ml][quad * 8];
    short8 b3 = *(const short8*)&Yt[48 + ml][quad * 8];
    acc0 = __builtin_amdgcn_mfma_f32_16x16x32_bf16(a, b0, acc0, 0, 0, 0);
    acc1 = __builtin_amdgcn_mfma_f32_16x16x32_bf16(a, b1, acc1, 0, 0, 0);
    acc2 = __builtin_amdgcn_mfma_f32_16x16x32_bf16(a, b2, acc2, 0, 0, 0);
    acc3 = __builtin_amdgcn_mfma_f32_16x16x32_bf16(a, b3, acc3, 0, 0, 0);
    __syncthreads();
  }

  int row_base = m0 + w * 16 + quad * 4;
  #pragma unroll
  for (int c = 0; c < 4; ++c) {
    floatx4 acc = (c == 0) ? acc0 : (c == 1) ? acc1 : (c == 2) ? acc2 : acc3;
    int col = n0 + c * 16 + ml;
    #pragma unroll
    for (int r = 0; r < 4; ++r) {
      int row = row_base + r;
      float v = acc[r] + bias[row];
      if (do_relu6) v = fminf(fmaxf(v, 0.f), 6.f);
      if (res) v += res[(size_t)b * M * NTOK + (size_t)row * NTOK + col];
      if (OT) {
        size_t oidx = (((size_t)b * 16 + (row >> 4)) * 1024 + col) * 16 + (row & 15);
        ((unsigned short*)outv)[oidx] = f2b(v);
      } else {
        size_t oidx = (size_t)b * out_bstride + (size_t)(out_row_off + row) * NTOK + col;
        if (OB) ((unsigned short*)outv)[oidx] = f2b(v);
        else    ((float*)outv)[oidx] = v;
      }
    }
  }
}

// ---------------------------------------------------------------------------
// Attention v3: one block per (b, h, 16-row n-tile). 8192 blocks, 4 waves.
// Phase 1: wave w computes S^T tiles (A=K-frag i=m, B=Q-frag j=n) for its
//   m-range w*256..+255.  C-layout gives lane 4 consecutive m at row n=ml ->
//   softmax rows reduce with 2 shuffles; P written as packed b64 (bank-floor).
//   P stored UNNORMALIZED; row sums kept in LDS, applied in phase-2 epilogue.
// Phase 2: wave w computes d-tile w*16: O = P~ @ V, K=1024, 4 indep accs.
// ---------------------------------------------------------------------------
__global__ __launch_bounds__(256, 4) void attn_kernel(
    const unsigned short* __restrict__ qt, const unsigned short* __restrict__ kt,
    const unsigned short* __restrict__ vt, unsigned short* __restrict__ ot) {
  int bx = blockIdx.x;
  int nt = bx & 63, h = (bx >> 6) & 15, b = bx >> 10;
  int t = threadIdx.x, lane = t & 63, w = t >> 6;
  int ml = lane & 15, quad = lane >> 4;
  __shared__ unsigned short P[16][1032];   // [n][m], stride 516 dw (4 mod 32)
  __shared__ float Mw[4][16];
  __shared__ float Sw[4][16];

  // ---- phase 1: S^T = K Q^T via MFMA ----
  const size_t qbase = (((size_t)b * 16 + h) * 1024 + (size_t)nt * 16) * 16;
  const size_t kbase = (((size_t)b * 16 + h) * 1024 + (size_t)w * 256) * 16;

  short8 qfrag = {0, 0, 0, 0, 0, 0, 0, 0};   // B[k=kd=quad*8+j][j=n=ml]
  if (quad < 2) qfrag = *(const short8*)(qt + qbase + (size_t)ml * 16 + quad * 8);

  floatx4 acc[16];
  #pragma unroll
  for (int i = 0; i < 16; ++i) acc[i] = (floatx4){0.f, 0.f, 0.f, 0.f};

  #pragma unroll
  for (int ti = 0; ti < 16; ++ti) {
    short8 kfrag = {0, 0, 0, 0, 0, 0, 0, 0}; // A[i=m=ml][k=kd=quad*8+j]
    if (quad < 2)
      kfrag = *(const short8*)(kt + kbase + ((size_t)ti * 16 + ml) * 16 + quad * 8);
    acc[ti] = __builtin_amdgcn_mfma_f32_16x16x32_bf16(kfrag, qfrag, acc[ti], 0, 0, 0);
  }
  // lane: acc[ti][r] = S[n=ml][m = w*256 + ti*16 + quad*4 + r]

  const float SC = 5.770780163555851f;   // 4 * log2(e): softmax(4*S) via exp2
  float mx = -3.0e38f;
  #pragma unroll
  for (int ti = 0; ti < 16; ++ti)
    #pragma unroll
    for (int r = 0; r < 4; ++r) mx = fmaxf(mx, acc[ti][r]);
  mx = fmaxf(mx, __shfl_xor(mx, 16, 64));
  mx = fmaxf(mx, __shfl_xor(mx, 32, 64));
  if (lane < 16) Mw[w][lane] = mx;
  __syncthreads();

  float gm = fmaxf(fmaxf(Mw[0][ml], Mw[1][ml]), fmaxf(Mw[2][ml], Mw[3][ml]));
  float sum = 0.f;
  #pragma unroll
  for (int ti = 0; ti < 16; ++ti)
    #pragma unroll
    for (int r = 0; r < 4; ++r) {
      float p = __builtin_amdgcn_exp2f((acc[ti][r] - gm) * SC);
      acc[ti][r] = p; sum += p;
    }
  sum += __shfl_xor(sum, 16, 64);
  sum += __shfl_xor(sum, 32, 64);
  if (lane < 16) Sw[w][lane] = sum;
  #pragma unroll
  for (int ti = 0; ti < 16; ++ti) {
    uint2 pw;
    pw.x = f2b2(acc[ti][0], acc[ti][1]);
    pw.y = f2b2(acc[ti][2], acc[ti][3]);
    *(uint2*)&P[ml][w * 256 + ti * 16 + quad * 4] = pw;   // b64, bank-floor
  }
  __syncthreads();

  // ---- phase 2: O = P~ @ V (4 independent acc chains) ----
  const size_t headv = ((size_t)b * 1024 + h * 64) * 1024;
  int d0 = w * 16;
  floatx4 oa0 = {0.f, 0.f, 0.f, 0.f}, oa1 = oa0, oa2 = oa0, oa3 = oa0;
  const unsigned short* vp = vt + headv + (size_t)(d0 + ml) * 1024 + quad * 8;
  #pragma unroll
  for (int kk = 0; kk < 32; kk += 4) {
    short8 a0 = *(const short8*)&P[ml][(kk + 0) * 32 + quad * 8];
    short8 a1 = *(const short8*)&P[ml][(kk + 1) * 32 + quad * 8];
    short8 a2 = *(const short8*)&P[ml][(kk + 2) * 32 + quad * 8];
    short8 a3 = *(const short8*)&P[ml][(kk + 3) * 32 + quad * 8];
    short8 b0 = *(const short8*)(vp + (size_t)(kk + 0) * 32);
    short8 b1 = *(const short8*)(vp + (size_t)(kk + 1) * 32);
    short8 b2 = *(const short8*)(vp + (size_t)(kk + 2) * 32);
    short8 b3 = *(const short8*)(vp + (size_t)(kk + 3) * 32);
    oa0 = __builtin_amdgcn_mfma_f32_16x16x32_bf16(a0, b0, oa0, 0, 0, 0);
    oa1 = __builtin_amdgcn_mfma_f32_16x16x32_bf16(a1, b1, oa1, 0, 0, 0);
    oa2 = __builtin_amdgcn_mfma_f32_16x16x32_bf16(a2, b2, oa2, 0, 0, 0);
    oa3 = __builtin_amdgcn_mfma_f32_16x16x32_bf16(a3, b3, oa3, 0, 0, 0);
  }
  // combine + deferred softmax normalization (row n = quad*4+r)
  float4 sw0 = *(const float4*)&Sw[0][quad * 4];
  float4 sw1 = *(const float4*)&Sw[1][quad * 4];
  float4 sw2 = *(const float4*)&Sw[2][quad * 4];
  float4 sw3 = *(const float4*)&Sw[3][quad * 4];
  float l0 = (sw0.x + sw1.x) + (sw2.x + sw3.x);
  float l1 = (sw0.y + sw1.y) + (sw2.y + sw3.y);
  float l2 = (sw0.z + sw1.z) + (sw2.z + sw3.z);
  float l3 = (sw0.w + sw1.w) + (sw2.w + sw3.w);
  floatx4 oacc;
  oacc[0] = (oa0[0] + oa1[0] + oa2[0] + oa3[0]) / l0;
  oacc[1] = (oa0[1] + oa1[1] + oa2[1] + oa3[1]) / l1;
  oacc[2] = (oa0[2] + oa1[2] + oa2[2] + oa3[2]) / l2;
  oacc[3] = (oa0[3] + oa1[3] + oa2[3] + oa3[3]) / l3;

  int dg = h * 64 + d0 + ml;
  #pragma unroll
  for (int r = 0; r < 4; ++r) {
    int n = nt * 16 + quad * 4 + r;
    ot[(((size_t)b << 10) + n) * 1024 + dg] = f2b(oacc[r]);
  }
}

// ---------------------------------------------------------------------------
extern "C" void kernel_launch(void* const* d_in, const int* in_sizes, int n_in,
                              void* d_out, int out_size, void* d_ws, size_t ws_size,
                              hipStream_t stream) {
  const float* x   = (const float*)d_in[0];
  const float* g1  = (const float*)d_in[1];
  const float* b1  = (const float*)d_in[2];
  const float* wq  = (const float*)d_in[3];
  const float* bq  = (const float*)d_in[4];
  const float* wk  = (const float*)d_in[5];
  const float* bk  = (const float*)d_in[6];
  const float* wv  = (const float*)d_in[7];
  const float* bv  = (const float*)d_in[8];
  const float* wp  = (const float*)d_in[9];
  const float* bp  = (const float*)d_in[10];
  const float* g2  = (const float*)d_in[11];
  const float* b2  = (const float*)d_in[12];
  const float* w1  = (const float*)d_in[13];
  const float* bb1 = (const float*)d_in[14];
  const float* w2  = (const float*)d_in[15];
  const float* bb2 = (const float*)d_in[16];

  char* ws = (char*)d_ws;
  float* sc1 = (float*)ws;
  float* sh1 = sc1 + 256;
  float* sc2 = sh1 + 256;
  float* sh2 = sc2 + 256;
  unsigned short* y   = (unsigned short*)(ws + 4096);     // bf16 [8][256][1024]
  unsigned short* qt  = y   + (size_t)2 * 1024 * 1024;    // bf16 [8][16][1024][16]
  unsigned short* kt  = qt  + (size_t)2 * 1024 * 1024;    // bf16 [8][16][1024][16]
  unsigned short* vt  = kt  + (size_t)2 * 1024 * 1024;    // bf16 [8][1024][1024]
  unsigned short* ot  = vt  + (size_t)8 * 1024 * 1024;    // bf16 [8][1024][1024]
  float*          xf1 = (float*)(ot + (size_t)8 * 1024 * 1024);  // f32 [8][256][1024]
  unsigned short* wb  = (unsigned short*)(xf1 + (size_t)2 * 1024 * 1024); // bf16 weights
  unsigned short* hb  = ot;                               // reuse (o_t dead after proj)
  float* outp = (float*)d_out;
  const float* nul = nullptr;

  unsigned short* wqb = wb;
  unsigned short* wkb = wb + 65536;
  unsigned short* wvb = wb + 131072;
  unsigned short* wpb = wb + 393216;
  unsigned short* w1b = wb + 655360;
  unsigned short* w2b = wb + 917504;

  cvt_weights<<<dim3(1152), dim3(256), 0, stream>>>(wq, wk, wv, wp, w1, w2, wb);

  // --- attention branch ---
  bn_stats<<<dim3(256), dim3(256), 0, stream>>>(x, g1, b1, sc1, sh1);
  bn_apply<<<dim3(2048), dim3(256), 0, stream>>>(x, sc1, sh1, y);
  gemm_mfma<0, 1, 1><<<dim3(16, 4, 8), dim3(256), 0, stream>>>(
      wqb, y, bq, nul, qt, 256, 256, 256ll * 1024, 0, 0, 0);
  gemm_mfma<0, 1, 1><<<dim3(16, 4, 8), dim3(256), 0, stream>>>(
      wkb, y, bk, nul, kt, 256, 256, 256ll * 1024, 0, 0, 0);
  gemm_mfma<0, 1, 0><<<dim3(16, 16, 8), dim3(256), 0, stream>>>(
      wvb, y, bv, nul, vt, 1024, 256, 256ll * 1024, 1024ll * 1024, 0, 0);
  attn_kernel<<<dim3(8192), dim3(256), 0, stream>>>(qt, kt, vt, ot);
  gemm_mfma<1, 0, 0><<<dim3(16, 4, 8), dim3(256), 0, stream>>>(
      wpb, ot, bp, x, xf1, 256, 1024, 1024ll * 1024, 256ll * 1024, 0, 0);

  // --- MLP branch ---
  bn_stats<<<dim3(256), dim3(256), 0, stream>>>(xf1, g2, b2, sc2, sh2);
  bn_apply<<<dim3(2048), dim3(256), 0, stream>>>(xf1, sc2, sh2, y);
  gemm_mfma<0, 1, 0><<<dim3(16, 16, 8), dim3(256), 0, stream>>>(
      w1b, y, bb1, nul, hb, 1024, 256, 256ll * 1024, 1024ll * 1024, 0, 1);
  gemm_mfma<0, 0, 0><<<dim3(16, 4, 8), dim3(256), 0, stream>>>(
      w2b, hb, bb2, xf1, outp, 256, 1024, 1024ll * 1024, 256ll * 1024, 0, 0);
}